// Round 1
// baseline (754.986 us; speedup 1.0000x reference)
//
#include <hip/hip_runtime.h>
#include <hip/hip_bf16.h>

#define N_NODES 100000
#define N_EDGES 1600000
#define C 128

// ---------------- degree count ----------------
__global__ __launch_bounds__(256) void deg_count(const int* __restrict__ dst,
                                                 int* __restrict__ deg, int E) {
    int i = blockIdx.x * 256 + threadIdx.x;
    if (i < E) atomicAdd(&deg[dst[i]], 1);
}

__global__ __launch_bounds__(256) void make_inv_sqrt(const int* __restrict__ deg,
                                                     float* __restrict__ isq, int n) {
    int i = blockIdx.x * 256 + threadIdx.x;
    if (i < n) isq[i] = rsqrtf((float)deg[i] + 1.0f);
}

// ---------------- exclusive scan (3-kernel) ----------------
__global__ __launch_bounds__(256) void scan_block(const int* __restrict__ deg,
                                                  int* __restrict__ rowptr,
                                                  int* __restrict__ partial, int n) {
    __shared__ int s[256];
    int tid = threadIdx.x;
    int i = blockIdx.x * 256 + tid;
    int v = (i < n) ? deg[i] : 0;
    s[tid] = v;
    __syncthreads();
    for (int off = 1; off < 256; off <<= 1) {
        int t = (tid >= off) ? s[tid - off] : 0;
        __syncthreads();
        s[tid] += t;
        __syncthreads();
    }
    if (i < n) rowptr[i] = s[tid] - v;           // block-local exclusive
    if (tid == 255) partial[blockIdx.x] = s[255]; // block total
}

__global__ __launch_bounds__(512) void scan_partial(int* __restrict__ partial, int n) {
    __shared__ int s[512];
    int tid = threadIdx.x;
    int v = (tid < n) ? partial[tid] : 0;
    s[tid] = v;
    __syncthreads();
    for (int off = 1; off < 512; off <<= 1) {
        int t = (tid >= off) ? s[tid - off] : 0;
        __syncthreads();
        s[tid] += t;
        __syncthreads();
    }
    if (tid < n) partial[tid] = s[tid] - v;       // exclusive
}

__global__ __launch_bounds__(256) void scan_finalize(int* __restrict__ rowptr,
                                                     int* __restrict__ cursor,
                                                     const int* __restrict__ partial,
                                                     int n, int E) {
    int i = blockIdx.x * 256 + threadIdx.x;
    if (i < n) {
        int v = rowptr[i] + partial[blockIdx.x];
        rowptr[i] = v;
        cursor[i] = v;
    }
    if (i == 0) rowptr[n] = E;
}

// ---------------- CSR fill ----------------
__global__ __launch_bounds__(256) void fill_csr(const int* __restrict__ src,
                                                const int* __restrict__ dst,
                                                int* __restrict__ cursor,
                                                int* __restrict__ col, int E) {
    int i = blockIdx.x * 256 + threadIdx.x;
    if (i < E) {
        int d = dst[i];
        int pos = atomicAdd(&cursor[d], 1);
        col[pos] = src[i];
    }
}

// ---------------- fp32 GEMM: C[M,128] = A[M,128] @ W[128,128] ----------------
// 32 rows per block, 256 threads, each thread 4x4 outputs. W read via L1/L2.
__global__ __launch_bounds__(256) void gemm128(const float* __restrict__ A,
                                               const float* __restrict__ W,
                                               float* __restrict__ Cout) {
    __shared__ float xs[32 * 128];  // 16 KB
    int tid = threadIdx.x;
    int m0 = blockIdx.x * 32;

    const float4* src4 = (const float4*)(A + (size_t)m0 * C);
    float4* xs4 = (float4*)xs;
#pragma unroll
    for (int j = 0; j < 4; j++) xs4[tid + j * 256] = src4[tid + j * 256];
    __syncthreads();

    int tx = tid & 31;   // col group: cols tx*4 .. tx*4+3
    int ty = tid >> 5;   // row group: rows ty*4 .. ty*4+3
    int c0 = tx * 4;
    int r0 = ty * 4;

    float acc[4][4] = {};
#pragma unroll 4
    for (int k = 0; k < 128; k++) {
        float4 w = *(const float4*)(W + k * C + c0);
        float a0 = xs[(r0 + 0) * 128 + k];
        float a1 = xs[(r0 + 1) * 128 + k];
        float a2 = xs[(r0 + 2) * 128 + k];
        float a3 = xs[(r0 + 3) * 128 + k];
        acc[0][0] += a0 * w.x; acc[0][1] += a0 * w.y; acc[0][2] += a0 * w.z; acc[0][3] += a0 * w.w;
        acc[1][0] += a1 * w.x; acc[1][1] += a1 * w.y; acc[1][2] += a1 * w.z; acc[1][3] += a1 * w.w;
        acc[2][0] += a2 * w.x; acc[2][1] += a2 * w.y; acc[2][2] += a2 * w.z; acc[2][3] += a2 * w.w;
        acc[3][0] += a3 * w.x; acc[3][1] += a3 * w.y; acc[3][2] += a3 * w.z; acc[3][3] += a3 * w.w;
    }
#pragma unroll
    for (int i = 0; i < 4; i++) {
        float4 o = {acc[i][0], acc[i][1], acc[i][2], acc[i][3]};
        *(float4*)(Cout + (size_t)(m0 + r0 + i) * C + c0) = o;
    }
}

// ---------------- aggregation: one wave per dst node ----------------
template <bool RELU>
__global__ __launch_bounds__(256) void aggregate(const float* __restrict__ h,
                                                 const int* __restrict__ rowptr,
                                                 const int* __restrict__ col,
                                                 const float* __restrict__ isq,
                                                 const float* __restrict__ bias,
                                                 float* __restrict__ out, int n) {
    int lane = threadIdx.x & 63;
    int wave = threadIdx.x >> 6;
    int node = blockIdx.x * 4 + wave;
    if (node >= n) return;

    float invd = isq[node];
    int beg = rowptr[node];
    int end = rowptr[node + 1];
    int cb = lane * 2;

    float ax = 0.f, ay = 0.f;
    for (int j = beg; j < end; j++) {
        int s = col[j];
        float cf = isq[s] * invd;
        float2 hv = *(const float2*)(h + (size_t)s * C + cb);
        ax += cf * hv.x;
        ay += cf * hv.y;
    }
    // self loop: coef = 1/deg
    float2 hd = *(const float2*)(h + (size_t)node * C + cb);
    float sc = invd * invd;
    ax += sc * hd.x;
    ay += sc * hd.y;

    float2 bv = *(const float2*)(bias + cb);
    ax += bv.x;
    ay += bv.y;
    if (RELU) {
        ax = fmaxf(ax, 0.f);
        ay = fmaxf(ay, 0.f);
    }
    float2 o = {ax, ay};
    *(float2*)(out + (size_t)node * C + cb) = o;
}

extern "C" void kernel_launch(void* const* d_in, const int* in_sizes, int n_in,
                              void* d_out, int out_size, void* d_ws, size_t ws_size,
                              hipStream_t stream) {
    const float* x  = (const float*)d_in[0];
    const int* ei   = (const int*)d_in[1];   // [2, E] int
    const float* W1 = (const float*)d_in[2];
    const float* b1 = (const float*)d_in[3];
    const float* W2 = (const float*)d_in[4];
    const float* b2 = (const float*)d_in[5];
    float* out = (float*)d_out;

    const int N = N_NODES, E = N_EDGES;
    const int* src = ei;
    const int* dst = ei + E;

    // workspace layout
    char* ws = (char*)d_ws;
    size_t off = 0;
    auto alloc = [&](size_t bytes) {
        size_t o = off;
        off = (off + bytes + 255) & ~(size_t)255;
        return o;
    };
    float* hA     = (float*)(ws + alloc((size_t)N * C * 4));
    float* hB     = (float*)(ws + alloc((size_t)N * C * 4));
    int*   deg    = (int*)  (ws + alloc((size_t)N * 4));
    float* isq    = (float*)(ws + alloc((size_t)N * 4));
    int*   rowptr = (int*)  (ws + alloc((size_t)(N + 1) * 4));
    int*   cursor = (int*)  (ws + alloc((size_t)N * 4));
    int*   part   = (int*)  (ws + alloc((size_t)512 * 4));
    int*   colv   = (int*)  (ws + alloc((size_t)E * 4));
    (void)ws_size; (void)n_in; (void)in_sizes; (void)out_size;

    const int nbN = (N + 255) / 256;   // 391
    const int nbE = (E + 255) / 256;   // 6250

    // degree + inv-sqrt
    hipMemsetAsync(deg, 0, (size_t)N * 4, stream);
    deg_count<<<nbE, 256, 0, stream>>>(dst, deg, E);
    make_inv_sqrt<<<nbN, 256, 0, stream>>>(deg, isq, N);

    // CSR build
    scan_block<<<nbN, 256, 0, stream>>>(deg, rowptr, part, N);
    scan_partial<<<1, 512, 0, stream>>>(part, nbN);
    scan_finalize<<<nbN, 256, 0, stream>>>(rowptr, cursor, part, N, E);
    fill_csr<<<nbE, 256, 0, stream>>>(src, dst, cursor, colv, E);

    // layer 1: h = x @ W1 ; agg + b1 + relu -> hB
    gemm128<<<N / 32, 256, 0, stream>>>(x, W1, hA);
    aggregate<true><<<(N + 3) / 4, 256, 0, stream>>>(hA, rowptr, colv, isq, b1, hB, N);

    // layer 2: h = hB @ W2 ; agg + b2 -> out
    gemm128<<<N / 32, 256, 0, stream>>>(hB, W2, hA);
    aggregate<false><<<(N + 3) / 4, 256, 0, stream>>>(hA, rowptr, colv, isq, b2, out, N);
}

// Round 2
// 626.189 us; speedup vs baseline: 1.2057x; 1.2057x over previous
//
#include <hip/hip_runtime.h>
#include <hip/hip_bf16.h>

#define N_NODES 100000
#define N_EDGES 1600000
#define C 128

// ---------------- degree count ----------------
__global__ __launch_bounds__(256) void deg_count(const int* __restrict__ dst,
                                                 int* __restrict__ deg, int E) {
    int i = blockIdx.x * 256 + threadIdx.x;
    if (i < E) atomicAdd(&deg[dst[i]], 1);
}

__global__ __launch_bounds__(256) void make_inv_sqrt(const int* __restrict__ deg,
                                                     float* __restrict__ isq, int n) {
    int i = blockIdx.x * 256 + threadIdx.x;
    if (i < n) isq[i] = rsqrtf((float)deg[i] + 1.0f);
}

// ---------------- exclusive scan (3-kernel) ----------------
__global__ __launch_bounds__(256) void scan_block(const int* __restrict__ deg,
                                                  int* __restrict__ rowptr,
                                                  int* __restrict__ partial, int n) {
    __shared__ int s[256];
    int tid = threadIdx.x;
    int i = blockIdx.x * 256 + tid;
    int v = (i < n) ? deg[i] : 0;
    s[tid] = v;
    __syncthreads();
    for (int off = 1; off < 256; off <<= 1) {
        int t = (tid >= off) ? s[tid - off] : 0;
        __syncthreads();
        s[tid] += t;
        __syncthreads();
    }
    if (i < n) rowptr[i] = s[tid] - v;           // block-local exclusive
    if (tid == 255) partial[blockIdx.x] = s[255]; // block total
}

__global__ __launch_bounds__(512) void scan_partial(int* __restrict__ partial, int n) {
    __shared__ int s[512];
    int tid = threadIdx.x;
    int v = (tid < n) ? partial[tid] : 0;
    s[tid] = v;
    __syncthreads();
    for (int off = 1; off < 512; off <<= 1) {
        int t = (tid >= off) ? s[tid - off] : 0;
        __syncthreads();
        s[tid] += t;
        __syncthreads();
    }
    if (tid < n) partial[tid] = s[tid] - v;       // exclusive
}

__global__ __launch_bounds__(256) void scan_finalize(int* __restrict__ rowptr,
                                                     int* __restrict__ cursor,
                                                     const int* __restrict__ partial,
                                                     int n, int E) {
    int i = blockIdx.x * 256 + threadIdx.x;
    if (i < n) {
        int v = rowptr[i] + partial[blockIdx.x];
        rowptr[i] = v;
        cursor[i] = v;
    }
    if (i == 0) rowptr[n] = E;
}

// ---------------- CSR fill (also precompute per-edge coefficient) ----------------
__global__ __launch_bounds__(256) void fill_csr(const int* __restrict__ src,
                                                const int* __restrict__ dst,
                                                const float* __restrict__ isq,
                                                int* __restrict__ cursor,
                                                int* __restrict__ col,
                                                float* __restrict__ coef, int E) {
    int i = blockIdx.x * 256 + threadIdx.x;
    if (i < E) {
        int d = dst[i];
        int s = src[i];
        int pos = atomicAdd(&cursor[d], 1);
        col[pos] = s;
        coef[pos] = isq[s] * isq[d];
    }
}

// ---------------- fp32 GEMM: C[M,128] = A[M,128] @ W[128,128] ----------------
// 32 rows per block, 256 threads, 4x4 outputs/thread. A-tile transposed in LDS
// so the inner loop reads 4 rows with ONE ds_read_b128 (was 4x ds_read_b32).
__global__ __launch_bounds__(256) void gemm128(const float* __restrict__ A,
                                               const float* __restrict__ W,
                                               float* __restrict__ Cout) {
    __shared__ float xsT[128 * 32];  // [k][row], 16 KB
    int tid = threadIdx.x;
    int m0 = blockIdx.x * 32;

    // stage + transpose: thread (r = tid&31, g = tid>>5) loads A[m0+r][g*16 .. g*16+15]
    {
        int r = tid & 31;
        int g = tid >> 5;
        const float* arow = A + (size_t)(m0 + r) * C + g * 16;
#pragma unroll
        for (int q = 0; q < 4; q++) {
            float4 v = *(const float4*)(arow + q * 4);
            int k0 = g * 16 + q * 4;
            // lanes 0..31 write consecutive r at fixed k -> conflict-free
            xsT[(k0 + 0) * 32 + r] = v.x;
            xsT[(k0 + 1) * 32 + r] = v.y;
            xsT[(k0 + 2) * 32 + r] = v.z;
            xsT[(k0 + 3) * 32 + r] = v.w;
        }
    }
    __syncthreads();

    int tx = tid & 31;   // col group: cols tx*4 .. tx*4+3
    int ty = tid >> 5;   // row group: rows ty*4 .. ty*4+3
    int c0 = tx * 4;
    int r0 = ty * 4;

    float acc[4][4] = {};
#pragma unroll 4
    for (int k = 0; k < 128; k++) {
        float4 a = *(const float4*)(xsT + k * 32 + r0);   // 4 rows, one b128
        float4 w = *(const float4*)(W + k * C + c0);      // 4 cols, L1/L2
        acc[0][0] += a.x * w.x; acc[0][1] += a.x * w.y; acc[0][2] += a.x * w.z; acc[0][3] += a.x * w.w;
        acc[1][0] += a.y * w.x; acc[1][1] += a.y * w.y; acc[1][2] += a.y * w.z; acc[1][3] += a.y * w.w;
        acc[2][0] += a.z * w.x; acc[2][1] += a.z * w.y; acc[2][2] += a.z * w.z; acc[2][3] += a.z * w.w;
        acc[3][0] += a.w * w.x; acc[3][1] += a.w * w.y; acc[3][2] += a.w * w.z; acc[3][3] += a.w * w.w;
    }
#pragma unroll
    for (int i = 0; i < 4; i++) {
        float4 o = {acc[i][0], acc[i][1], acc[i][2], acc[i][3]};
        *(float4*)(Cout + (size_t)(m0 + r0 + i) * C + c0) = o;
    }
}

// ---------------- aggregation: one wave per dst node ----------------
// 32 lanes cover one h row (float4/lane); the two lane-halves process two
// edges concurrently; unroll x2 => 4 independent 512B row-gathers in flight.
template <bool RELU>
__global__ __launch_bounds__(256) void aggregate(const float* __restrict__ h,
                                                 const int* __restrict__ rowptr,
                                                 const int* __restrict__ col,
                                                 const float* __restrict__ coef,
                                                 const float* __restrict__ isq,
                                                 const float* __restrict__ bias,
                                                 float* __restrict__ out, int n) {
    int lane = threadIdx.x & 63;
    int wave = threadIdx.x >> 6;
    int node = blockIdx.x * 4 + wave;
    if (node >= n) return;

    int half = lane >> 5;   // which edge of the pair this half-wave handles
    int l32  = lane & 31;
    int cb   = l32 * 4;

    int beg = rowptr[node];
    int end = rowptr[node + 1];

    float4 acc = {0.f, 0.f, 0.f, 0.f};

    int j = beg + half;
    for (; j + 2 < end; j += 4) {
        int   s0 = col[j];
        float c0 = coef[j];
        int   s1 = col[j + 2];
        float c1 = coef[j + 2];
        float4 h0 = *(const float4*)(h + (size_t)s0 * C + cb);
        float4 h1 = *(const float4*)(h + (size_t)s1 * C + cb);
        acc.x += c0 * h0.x; acc.y += c0 * h0.y; acc.z += c0 * h0.z; acc.w += c0 * h0.w;
        acc.x += c1 * h1.x; acc.y += c1 * h1.y; acc.z += c1 * h1.z; acc.w += c1 * h1.w;
    }
    for (; j < end; j += 2) {
        int   s = col[j];
        float cf = coef[j];
        float4 hv = *(const float4*)(h + (size_t)s * C + cb);
        acc.x += cf * hv.x; acc.y += cf * hv.y; acc.z += cf * hv.z; acc.w += cf * hv.w;
    }

    // combine the two half-wave accumulators (cols are identical across halves)
    acc.x += __shfl_xor(acc.x, 32, 64);
    acc.y += __shfl_xor(acc.y, 32, 64);
    acc.z += __shfl_xor(acc.z, 32, 64);
    acc.w += __shfl_xor(acc.w, 32, 64);

    if (half == 0) {
        float invd = isq[node];
        float sc = invd * invd;                       // self-loop coef = 1/deg
        float4 hd = *(const float4*)(h + (size_t)node * C + cb);
        float4 bv = *(const float4*)(bias + cb);
        acc.x += sc * hd.x + bv.x;
        acc.y += sc * hd.y + bv.y;
        acc.z += sc * hd.z + bv.z;
        acc.w += sc * hd.w + bv.w;
        if (RELU) {
            acc.x = fmaxf(acc.x, 0.f);
            acc.y = fmaxf(acc.y, 0.f);
            acc.z = fmaxf(acc.z, 0.f);
            acc.w = fmaxf(acc.w, 0.f);
        }
        *(float4*)(out + (size_t)node * C + cb) = acc;
    }
}

extern "C" void kernel_launch(void* const* d_in, const int* in_sizes, int n_in,
                              void* d_out, int out_size, void* d_ws, size_t ws_size,
                              hipStream_t stream) {
    const float* x  = (const float*)d_in[0];
    const int* ei   = (const int*)d_in[1];   // [2, E] int
    const float* W1 = (const float*)d_in[2];
    const float* b1 = (const float*)d_in[3];
    const float* W2 = (const float*)d_in[4];
    const float* b2 = (const float*)d_in[5];
    float* out = (float*)d_out;

    const int N = N_NODES, E = N_EDGES;
    const int* src = ei;
    const int* dst = ei + E;

    // workspace layout
    char* ws = (char*)d_ws;
    size_t off = 0;
    auto alloc = [&](size_t bytes) {
        size_t o = off;
        off = (off + bytes + 255) & ~(size_t)255;
        return o;
    };
    float* hA     = (float*)(ws + alloc((size_t)N * C * 4));
    float* hB     = (float*)(ws + alloc((size_t)N * C * 4));
    int*   deg    = (int*)  (ws + alloc((size_t)N * 4));
    float* isq    = (float*)(ws + alloc((size_t)N * 4));
    int*   rowptr = (int*)  (ws + alloc((size_t)(N + 1) * 4));
    int*   cursor = (int*)  (ws + alloc((size_t)N * 4));
    int*   part   = (int*)  (ws + alloc((size_t)512 * 4));
    int*   colv   = (int*)  (ws + alloc((size_t)E * 4));
    float* coefv  = (float*)(ws + alloc((size_t)E * 4));
    (void)ws_size; (void)n_in; (void)in_sizes; (void)out_size;

    const int nbN = (N + 255) / 256;   // 391
    const int nbE = (E + 255) / 256;   // 6250

    // degree + inv-sqrt
    hipMemsetAsync(deg, 0, (size_t)N * 4, stream);
    deg_count<<<nbE, 256, 0, stream>>>(dst, deg, E);
    make_inv_sqrt<<<nbN, 256, 0, stream>>>(deg, isq, N);

    // CSR build
    scan_block<<<nbN, 256, 0, stream>>>(deg, rowptr, part, N);
    scan_partial<<<1, 512, 0, stream>>>(part, nbN);
    scan_finalize<<<nbN, 256, 0, stream>>>(rowptr, cursor, part, N, E);
    fill_csr<<<nbE, 256, 0, stream>>>(src, dst, isq, cursor, colv, coefv, E);

    // layer 1: h = x @ W1 ; agg + b1 + relu -> hB
    gemm128<<<N / 32, 256, 0, stream>>>(x, W1, hA);
    aggregate<true><<<(N + 3) / 4, 256, 0, stream>>>(hA, rowptr, colv, coefv, isq, b1, hB, N);

    // layer 2: h = hB @ W2 ; agg + b2 -> out
    gemm128<<<N / 32, 256, 0, stream>>>(hB, W2, hA);
    aggregate<false><<<(N + 3) / 4, 256, 0, stream>>>(hA, rowptr, colv, coefv, isq, b2, out, N);
}

// Round 3
// 525.244 us; speedup vs baseline: 1.4374x; 1.1922x over previous
//
#include <hip/hip_runtime.h>
#include <hip/hip_bf16.h>
#include <hip/hip_fp16.h>

#define N_NODES 100000
#define N_EDGES 1600000
#define C 128

typedef _Float16 half8 __attribute__((ext_vector_type(8)));

// ---------------- degree count ----------------
__global__ __launch_bounds__(256) void deg_count(const int* __restrict__ dst,
                                                 int* __restrict__ deg, int E) {
    int i = blockIdx.x * 256 + threadIdx.x;
    if (i < E) atomicAdd(&deg[dst[i]], 1);
}

__global__ __launch_bounds__(256) void make_inv_sqrt(const int* __restrict__ deg,
                                                     float* __restrict__ isq, int n) {
    int i = blockIdx.x * 256 + threadIdx.x;
    if (i < n) isq[i] = rsqrtf((float)deg[i] + 1.0f);
}

// ---------------- exclusive scan (3-kernel) ----------------
__global__ __launch_bounds__(256) void scan_block(const int* __restrict__ deg,
                                                  int* __restrict__ rowptr,
                                                  int* __restrict__ partial, int n) {
    __shared__ int s[256];
    int tid = threadIdx.x;
    int i = blockIdx.x * 256 + tid;
    int v = (i < n) ? deg[i] : 0;
    s[tid] = v;
    __syncthreads();
    for (int off = 1; off < 256; off <<= 1) {
        int t = (tid >= off) ? s[tid - off] : 0;
        __syncthreads();
        s[tid] += t;
        __syncthreads();
    }
    if (i < n) rowptr[i] = s[tid] - v;
    if (tid == 255) partial[blockIdx.x] = s[255];
}

__global__ __launch_bounds__(512) void scan_partial(int* __restrict__ partial, int n) {
    __shared__ int s[512];
    int tid = threadIdx.x;
    int v = (tid < n) ? partial[tid] : 0;
    s[tid] = v;
    __syncthreads();
    for (int off = 1; off < 512; off <<= 1) {
        int t = (tid >= off) ? s[tid - off] : 0;
        __syncthreads();
        s[tid] += t;
        __syncthreads();
    }
    if (tid < n) partial[tid] = s[tid] - v;
}

__global__ __launch_bounds__(256) void scan_finalize(int* __restrict__ rowptr,
                                                     int* __restrict__ cursor,
                                                     const int* __restrict__ partial,
                                                     int n, int E) {
    int i = blockIdx.x * 256 + threadIdx.x;
    if (i < n) {
        int v = rowptr[i] + partial[blockIdx.x];
        rowptr[i] = v;
        cursor[i] = v;
    }
    if (i == 0) rowptr[n] = E;
}

// ---------------- CSR fill: fused (src, coef) edge records ----------------
__global__ __launch_bounds__(256) void fill_csr(const int* __restrict__ src,
                                                const int* __restrict__ dst,
                                                const float* __restrict__ isq,
                                                int* __restrict__ cursor,
                                                int2* __restrict__ edges, int E) {
    int i = blockIdx.x * 256 + threadIdx.x;
    if (i < E) {
        int d = dst[i];
        int s = src[i];
        int pos = atomicAdd(&cursor[d], 1);
        edges[pos] = make_int2(s, __float_as_int(isq[s] * isq[d]));
    }
}

// ---------------- fp32 GEMM: out[M,128](fp16) = A[M,128](fp32) @ W[128,128] ----
// 64 rows/block, 256 threads, per-thread 4 rows x 8 cols: per k one ds_read_b128
// feeds 32 FMAs (2x the FLOP/LDS-instr of the old 4x4 tile).
__global__ __launch_bounds__(256) void gemm128(const float* __restrict__ A,
                                               const float* __restrict__ W,
                                               _Float16* __restrict__ Cout, int n) {
    __shared__ float xsT[128 * 64];  // [k][row], 32 KB
    int tid = threadIdx.x;
    int m0 = blockIdx.x * 64;

    // stage + transpose: thread (r = tid&63, g = tid>>6) loads row m0+r, cols g*32..+31
    {
        int r = tid & 63;
        int g = tid >> 6;
        int row = m0 + r;
        if (row >= n) row = n - 1;             // clamp (stores are guarded)
        const float* arow = A + (size_t)row * C + g * 32;
#pragma unroll
        for (int q = 0; q < 8; q++) {
            float4 v = *(const float4*)(arow + q * 4);
            int k0 = g * 32 + q * 4;
            xsT[(k0 + 0) * 64 + r] = v.x;
            xsT[(k0 + 1) * 64 + r] = v.y;
            xsT[(k0 + 2) * 64 + r] = v.z;
            xsT[(k0 + 3) * 64 + r] = v.w;
        }
    }
    __syncthreads();

    int ty = tid & 15;    // row group: rows ty*4 .. ty*4+3
    int tx = tid >> 4;    // col group: cols tx*8 .. tx*8+7
    int r0 = ty * 4;
    int c0 = tx * 8;

    float acc[4][8] = {};
#pragma unroll 4
    for (int k = 0; k < 128; k++) {
        float4 a  = *(const float4*)(xsT + k * 64 + r0);
        float4 w0 = *(const float4*)(W + k * C + c0);
        float4 w1 = *(const float4*)(W + k * C + c0 + 4);
        float av[4] = {a.x, a.y, a.z, a.w};
        float wv[8] = {w0.x, w0.y, w0.z, w0.w, w1.x, w1.y, w1.z, w1.w};
#pragma unroll
        for (int i = 0; i < 4; i++)
#pragma unroll
            for (int j = 0; j < 8; j++)
                acc[i][j] += av[i] * wv[j];
    }
#pragma unroll
    for (int i = 0; i < 4; i++) {
        int row = m0 + r0 + i;
        if (row < n) {
            half8 o;
#pragma unroll
            for (int j = 0; j < 8; j++) o[j] = (_Float16)acc[i][j];
            *(half8*)(Cout + (size_t)row * C + c0) = o;
        }
    }
}

// ---------------- aggregation: one wave per dst node, fp16 h ----------------
// Quarter-wave (16 lanes x 16B) covers one 256B h row; 4 quarters x unroll 2
// = 8 independent row-gathers in flight per wave.
template <bool RELU>
__global__ __launch_bounds__(256) void aggregate(const _Float16* __restrict__ h,
                                                 const int* __restrict__ rowptr,
                                                 const int2* __restrict__ edges,
                                                 const float* __restrict__ isq,
                                                 const float* __restrict__ bias,
                                                 float* __restrict__ out, int n) {
    int lane = threadIdx.x & 63;
    int wave = threadIdx.x >> 6;
    int node = blockIdx.x * 4 + wave;
    if (node >= n) return;

    int q   = lane >> 4;       // quarter 0..3: which edge of the group
    int l16 = lane & 15;
    int cb  = l16 * 8;         // channel base (8 fp16 = 16 B per lane)

    int beg = rowptr[node];
    int end = rowptr[node + 1];

    float acc[8] = {};

    int j = beg + q;
    for (; j + 4 < end; j += 8) {
        int2 e0 = edges[j];
        int2 e1 = edges[j + 4];
        half8 h0 = *(const half8*)(h + (size_t)e0.x * C + cb);
        half8 h1 = *(const half8*)(h + (size_t)e1.x * C + cb);
        float cf0 = __int_as_float(e0.y);
        float cf1 = __int_as_float(e1.y);
#pragma unroll
        for (int k = 0; k < 8; k++) acc[k] += cf0 * (float)h0[k];
#pragma unroll
        for (int k = 0; k < 8; k++) acc[k] += cf1 * (float)h1[k];
    }
    for (; j < end; j += 4) {
        int2 e = edges[j];
        half8 hv = *(const half8*)(h + (size_t)e.x * C + cb);
        float cf = __int_as_float(e.y);
#pragma unroll
        for (int k = 0; k < 8; k++) acc[k] += cf * (float)hv[k];
    }

    // sum the 4 quarter-wave accumulators (channel layout identical across quarters)
#pragma unroll
    for (int k = 0; k < 8; k++) {
        acc[k] += __shfl_xor(acc[k], 16, 64);
        acc[k] += __shfl_xor(acc[k], 32, 64);
    }

    if (q == 0) {
        float invd = isq[node];
        float sc = invd * invd;                     // self-loop coef = 1/deg
        half8 hd = *(const half8*)(h + (size_t)node * C + cb);
        float4 bv0 = *(const float4*)(bias + cb);
        float4 bv1 = *(const float4*)(bias + cb + 4);
        float bb[8] = {bv0.x, bv0.y, bv0.z, bv0.w, bv1.x, bv1.y, bv1.z, bv1.w};
#pragma unroll
        for (int k = 0; k < 8; k++) {
            acc[k] += sc * (float)hd[k] + bb[k];
            if (RELU) acc[k] = fmaxf(acc[k], 0.f);
        }
        float4 o0 = {acc[0], acc[1], acc[2], acc[3]};
        float4 o1 = {acc[4], acc[5], acc[6], acc[7]};
        *(float4*)(out + (size_t)node * C + cb) = o0;
        *(float4*)(out + (size_t)node * C + cb + 4) = o1;
    }
}

extern "C" void kernel_launch(void* const* d_in, const int* in_sizes, int n_in,
                              void* d_out, int out_size, void* d_ws, size_t ws_size,
                              hipStream_t stream) {
    const float* x  = (const float*)d_in[0];
    const int* ei   = (const int*)d_in[1];   // [2, E] int
    const float* W1 = (const float*)d_in[2];
    const float* b1 = (const float*)d_in[3];
    const float* W2 = (const float*)d_in[4];
    const float* b2 = (const float*)d_in[5];
    float* out = (float*)d_out;

    const int N = N_NODES, E = N_EDGES;
    const int* src = ei;
    const int* dst = ei + E;

    // workspace layout
    char* ws = (char*)d_ws;
    size_t off = 0;
    auto alloc = [&](size_t bytes) {
        size_t o = off;
        off = (off + bytes + 255) & ~(size_t)255;
        return o;
    };
    _Float16* h16  = (_Float16*)(ws + alloc((size_t)N * C * 2));  // gemm out / agg in
    float*    hB   = (float*)   (ws + alloc((size_t)N * C * 4));  // agg1 out / gemm2 in
    int*      deg  = (int*)     (ws + alloc((size_t)N * 4));
    float*    isq  = (float*)   (ws + alloc((size_t)N * 4));
    int*    rowptr = (int*)     (ws + alloc((size_t)(N + 1) * 4));
    int*    cursor = (int*)     (ws + alloc((size_t)N * 4));
    int*    part   = (int*)     (ws + alloc((size_t)512 * 4));
    int2*   edges  = (int2*)    (ws + alloc((size_t)E * 8));
    (void)ws_size; (void)n_in; (void)in_sizes; (void)out_size;

    const int nbN = (N + 255) / 256;   // 391
    const int nbE = (E + 255) / 256;   // 6250
    const int nbG = (N + 63) / 64;     // 1563

    // degree + inv-sqrt
    hipMemsetAsync(deg, 0, (size_t)N * 4, stream);
    deg_count<<<nbE, 256, 0, stream>>>(dst, deg, E);
    make_inv_sqrt<<<nbN, 256, 0, stream>>>(deg, isq, N);

    // CSR build
    scan_block<<<nbN, 256, 0, stream>>>(deg, rowptr, part, N);
    scan_partial<<<1, 512, 0, stream>>>(part, nbN);
    scan_finalize<<<nbN, 256, 0, stream>>>(rowptr, cursor, part, N, E);
    fill_csr<<<nbE, 256, 0, stream>>>(src, dst, isq, cursor, edges, E);

    // layer 1: h16 = x @ W1 ; agg + b1 + relu -> hB
    gemm128<<<nbG, 256, 0, stream>>>(x, W1, h16, N);
    aggregate<true><<<(N + 3) / 4, 256, 0, stream>>>(h16, rowptr, edges, isq, b1, hB, N);

    // layer 2: h16 = hB @ W2 ; agg + b2 -> out
    gemm128<<<nbG, 256, 0, stream>>>(hB, W2, h16, N);
    aggregate<false><<<(N + 3) / 4, 256, 0, stream>>>(h16, rowptr, edges, isq, b2, out, N);
}

// Round 5
// 489.657 us; speedup vs baseline: 1.5419x; 1.0727x over previous
//
#include <hip/hip_runtime.h>
#include <hip/hip_bf16.h>
#include <hip/hip_fp16.h>

#define N_NODES 100000
#define N_EDGES 1600000
#define C 128

typedef _Float16 half8 __attribute__((ext_vector_type(8)));

// ---------------- degree count + per-edge rank ----------------
// The atomicAdd return value IS the edge's rank among its dst's edges --
// persisting it lets the fill pass run with zero atomics.
__global__ __launch_bounds__(256) void deg_rank(const int* __restrict__ dst,
                                                int* __restrict__ deg,
                                                int* __restrict__ rank, int E) {
    int i = blockIdx.x * 256 + threadIdx.x;
    if (i < E) rank[i] = atomicAdd(&deg[dst[i]], 1);
}

// ---------------- exclusive scan (3-kernel) ----------------
__global__ __launch_bounds__(256) void scan_block(const int* __restrict__ deg,
                                                  int* __restrict__ rowptr,
                                                  int* __restrict__ partial, int n) {
    __shared__ int s[256];
    int tid = threadIdx.x;
    int i = blockIdx.x * 256 + tid;
    int v = (i < n) ? deg[i] : 0;
    s[tid] = v;
    __syncthreads();
    for (int off = 1; off < 256; off <<= 1) {
        int t = (tid >= off) ? s[tid - off] : 0;
        __syncthreads();
        s[tid] += t;
        __syncthreads();
    }
    if (i < n) rowptr[i] = s[tid] - v;
    if (tid == 255) partial[blockIdx.x] = s[255];
}

__global__ __launch_bounds__(512) void scan_partial(int* __restrict__ partial, int n) {
    __shared__ int s[512];
    int tid = threadIdx.x;
    int v = (tid < n) ? partial[tid] : 0;
    s[tid] = v;
    __syncthreads();
    for (int off = 1; off < 512; off <<= 1) {
        int t = (tid >= off) ? s[tid - off] : 0;
        __syncthreads();
        s[tid] += t;
        __syncthreads();
    }
    if (tid < n) partial[tid] = s[tid] - v;
}

// finalize rowptr AND compute isq (fused, both are 1:1 over nodes)
__global__ __launch_bounds__(256) void scan_finalize(int* __restrict__ rowptr,
                                                     const int* __restrict__ partial,
                                                     const int* __restrict__ deg,
                                                     float* __restrict__ isq,
                                                     int n, int E) {
    int i = blockIdx.x * 256 + threadIdx.x;
    if (i < n) {
        rowptr[i] += partial[blockIdx.x];
        isq[i] = rsqrtf((float)deg[i] + 1.0f);
    }
    if (i == 0) rowptr[n] = E;
}

// ---------------- CSR fill: atomic-free scatter ----------------
__global__ __launch_bounds__(256) void fill_scatter(const int* __restrict__ src,
                                                    const int* __restrict__ dst,
                                                    const int* __restrict__ rank,
                                                    const int* __restrict__ rowptr,
                                                    const float* __restrict__ isq,
                                                    long long* __restrict__ edges, int E) {
    int i = blockIdx.x * 256 + threadIdx.x;
    if (i < E) {
        int d = dst[i];
        int s = src[i];
        int pos = rowptr[d] + rank[i];
        unsigned int cf = __float_as_uint(isq[s] * isq[d]);
        long long rec = (long long)(((unsigned long long)cf << 32) |
                                    (unsigned long long)(unsigned int)s);
        __builtin_nontemporal_store(rec, &edges[pos]);
    }
}

// ---------------- fp32 GEMM: out[M,128](fp16) = A[M,128](fp32) @ W[128,128] ----
__global__ __launch_bounds__(256) void gemm128(const float* __restrict__ A,
                                               const float* __restrict__ W,
                                               _Float16* __restrict__ Cout, int n) {
    __shared__ float xsT[128 * 64];  // [k][row], 32 KB
    int tid = threadIdx.x;
    int m0 = blockIdx.x * 64;

    {
        int r = tid & 63;
        int g = tid >> 6;
        int row = m0 + r;
        if (row >= n) row = n - 1;             // clamp (stores are guarded)
        const float* arow = A + (size_t)row * C + g * 32;
#pragma unroll
        for (int q = 0; q < 8; q++) {
            float4 v = *(const float4*)(arow + q * 4);
            int k0 = g * 32 + q * 4;
            xsT[(k0 + 0) * 64 + r] = v.x;
            xsT[(k0 + 1) * 64 + r] = v.y;
            xsT[(k0 + 2) * 64 + r] = v.z;
            xsT[(k0 + 3) * 64 + r] = v.w;
        }
    }
    __syncthreads();

    int ty = tid & 15;    // rows ty*4 .. ty*4+3
    int tx = tid >> 4;    // cols tx*8 .. tx*8+7
    int r0 = ty * 4;
    int c0 = tx * 8;

    float acc[4][8] = {};
#pragma unroll 4
    for (int k = 0; k < 128; k++) {
        float4 a  = *(const float4*)(xsT + k * 64 + r0);
        float4 w0 = *(const float4*)(W + k * C + c0);
        float4 w1 = *(const float4*)(W + k * C + c0 + 4);
        float av[4] = {a.x, a.y, a.z, a.w};
        float wv[8] = {w0.x, w0.y, w0.z, w0.w, w1.x, w1.y, w1.z, w1.w};
#pragma unroll
        for (int i = 0; i < 4; i++)
#pragma unroll
            for (int j = 0; j < 8; j++)
                acc[i][j] += av[i] * wv[j];
    }
#pragma unroll
    for (int i = 0; i < 4; i++) {
        int row = m0 + r0 + i;
        if (row < n) {
            half8 o;
#pragma unroll
            for (int j = 0; j < 8; j++) o[j] = (_Float16)acc[i][j];
            *(half8*)(Cout + (size_t)row * C + c0) = o;
        }
    }
}

// ---------------- aggregation: one wave per dst node, fp16 h ----------------
template <bool RELU>
__global__ __launch_bounds__(256) void aggregate(const _Float16* __restrict__ h,
                                                 const int* __restrict__ rowptr,
                                                 const long long* __restrict__ edges,
                                                 const float* __restrict__ isq,
                                                 const float* __restrict__ bias,
                                                 float* __restrict__ out, int n) {
    int lane = threadIdx.x & 63;
    int wave = threadIdx.x >> 6;
    int node = blockIdx.x * 4 + wave;
    if (node >= n) return;

    int q   = lane >> 4;       // quarter 0..3: which edge of the group
    int l16 = lane & 15;
    int cb  = l16 * 8;         // channel base (8 fp16 = 16 B per lane)

    int beg = rowptr[node];
    int end = rowptr[node + 1];

    float acc[8] = {};

    int j = beg + q;
    for (; j + 4 < end; j += 8) {
        unsigned long long e0 = (unsigned long long)edges[j];
        unsigned long long e1 = (unsigned long long)edges[j + 4];
        int s0 = (int)(unsigned int)e0;
        int s1 = (int)(unsigned int)e1;
        half8 h0 = *(const half8*)(h + (size_t)s0 * C + cb);
        half8 h1 = *(const half8*)(h + (size_t)s1 * C + cb);
        float cf0 = __uint_as_float((unsigned int)(e0 >> 32));
        float cf1 = __uint_as_float((unsigned int)(e1 >> 32));
#pragma unroll
        for (int k = 0; k < 8; k++) acc[k] += cf0 * (float)h0[k];
#pragma unroll
        for (int k = 0; k < 8; k++) acc[k] += cf1 * (float)h1[k];
    }
    for (; j < end; j += 4) {
        unsigned long long e = (unsigned long long)edges[j];
        int s = (int)(unsigned int)e;
        half8 hv = *(const half8*)(h + (size_t)s * C + cb);
        float cf = __uint_as_float((unsigned int)(e >> 32));
#pragma unroll
        for (int k = 0; k < 8; k++) acc[k] += cf * (float)hv[k];
    }

#pragma unroll
    for (int k = 0; k < 8; k++) {
        acc[k] += __shfl_xor(acc[k], 16, 64);
        acc[k] += __shfl_xor(acc[k], 32, 64);
    }

    if (q == 0) {
        float invd = isq[node];
        float sc = invd * invd;                     // self-loop coef = 1/deg
        half8 hd = *(const half8*)(h + (size_t)node * C + cb);
        float4 bv0 = *(const float4*)(bias + cb);
        float4 bv1 = *(const float4*)(bias + cb + 4);
        float bb[8] = {bv0.x, bv0.y, bv0.z, bv0.w, bv1.x, bv1.y, bv1.z, bv1.w};
#pragma unroll
        for (int k = 0; k < 8; k++) {
            acc[k] += sc * (float)hd[k] + bb[k];
            if (RELU) acc[k] = fmaxf(acc[k], 0.f);
        }
        float4 o0 = {acc[0], acc[1], acc[2], acc[3]};
        float4 o1 = {acc[4], acc[5], acc[6], acc[7]};
        *(float4*)(out + (size_t)node * C + cb) = o0;
        *(float4*)(out + (size_t)node * C + cb + 4) = o1;
    }
}

extern "C" void kernel_launch(void* const* d_in, const int* in_sizes, int n_in,
                              void* d_out, int out_size, void* d_ws, size_t ws_size,
                              hipStream_t stream) {
    const float* x  = (const float*)d_in[0];
    const int* ei   = (const int*)d_in[1];   // [2, E] int
    const float* W1 = (const float*)d_in[2];
    const float* b1 = (const float*)d_in[3];
    const float* W2 = (const float*)d_in[4];
    const float* b2 = (const float*)d_in[5];
    float* out = (float*)d_out;

    const int N = N_NODES, E = N_EDGES;
    const int* src = ei;
    const int* dst = ei + E;

    // workspace layout
    char* ws = (char*)d_ws;
    size_t off = 0;
    auto alloc = [&](size_t bytes) {
        size_t o = off;
        off = (off + bytes + 255) & ~(size_t)255;
        return o;
    };
    _Float16* h16  = (_Float16*)(ws + alloc((size_t)N * C * 2));  // gemm out / agg in
    float*    hB   = (float*)   (ws + alloc((size_t)N * C * 4));  // agg1 out / gemm2 in
    int*      deg  = (int*)     (ws + alloc((size_t)N * 4));
    float*    isq  = (float*)   (ws + alloc((size_t)N * 4));
    int*    rowptr = (int*)     (ws + alloc((size_t)(N + 1) * 4));
    int*    rank   = (int*)     (ws + alloc((size_t)E * 4));
    int*    part   = (int*)     (ws + alloc((size_t)512 * 4));
    long long* edges = (long long*)(ws + alloc((size_t)E * 8));
    (void)ws_size; (void)n_in; (void)in_sizes; (void)out_size;

    const int nbN = (N + 255) / 256;   // 391
    const int nbE = (E + 255) / 256;   // 6250
    const int nbG = (N + 63) / 64;     // 1563

    (void)hipMemsetAsync(deg, 0, (size_t)N * 4, stream);
    deg_rank<<<nbE, 256, 0, stream>>>(dst, deg, rank, E);

    // CSR build (atomic-free fill: pos = rowptr[dst] + rank)
    scan_block<<<nbN, 256, 0, stream>>>(deg, rowptr, part, N);
    scan_partial<<<1, 512, 0, stream>>>(part, nbN);
    scan_finalize<<<nbN, 256, 0, stream>>>(rowptr, part, deg, isq, N, E);
    fill_scatter<<<nbE, 256, 0, stream>>>(src, dst, rank, rowptr, isq, edges, E);

    // layer 1: h16 = x @ W1 ; agg + b1 + relu -> hB
    gemm128<<<nbG, 256, 0, stream>>>(x, W1, h16, N);
    aggregate<true><<<(N + 3) / 4, 256, 0, stream>>>(h16, rowptr, edges, isq, b1, hB, N);

    // layer 2: h16 = hB @ W2 ; agg + b2 -> out
    gemm128<<<nbG, 256, 0, stream>>>(hB, W2, h16, N);
    aggregate<false><<<(N + 3) / 4, 256, 0, stream>>>(h16, rowptr, edges, isq, b2, out, N);
}

// Round 6
// 395.999 us; speedup vs baseline: 1.9065x; 1.2365x over previous
//
#include <hip/hip_runtime.h>
#include <hip/hip_bf16.h>
#include <hip/hip_fp16.h>

#define N_NODES 100000
#define N_EDGES 1600000
#define C 128

typedef _Float16 half8 __attribute__((ext_vector_type(8)));
typedef _Float16 half4v __attribute__((ext_vector_type(4)));
typedef float f32x4 __attribute__((ext_vector_type(4)));

// ---------------- degree count + per-edge rank ----------------
__global__ __launch_bounds__(256) void deg_rank(const int* __restrict__ dst,
                                                int* __restrict__ deg,
                                                int* __restrict__ rank, int E) {
    int i = blockIdx.x * 256 + threadIdx.x;
    if (i < E) rank[i] = atomicAdd(&deg[dst[i]], 1);
}

// ---------------- exclusive scan (3-kernel) ----------------
__global__ __launch_bounds__(256) void scan_block(const int* __restrict__ deg,
                                                  int* __restrict__ rowptr,
                                                  int* __restrict__ partial, int n) {
    __shared__ int s[256];
    int tid = threadIdx.x;
    int i = blockIdx.x * 256 + tid;
    int v = (i < n) ? deg[i] : 0;
    s[tid] = v;
    __syncthreads();
    for (int off = 1; off < 256; off <<= 1) {
        int t = (tid >= off) ? s[tid - off] : 0;
        __syncthreads();
        s[tid] += t;
        __syncthreads();
    }
    if (i < n) rowptr[i] = s[tid] - v;
    if (tid == 255) partial[blockIdx.x] = s[255];
}

__global__ __launch_bounds__(512) void scan_partial(int* __restrict__ partial, int n) {
    __shared__ int s[512];
    int tid = threadIdx.x;
    int v = (tid < n) ? partial[tid] : 0;
    s[tid] = v;
    __syncthreads();
    for (int off = 1; off < 512; off <<= 1) {
        int t = (tid >= off) ? s[tid - off] : 0;
        __syncthreads();
        s[tid] += t;
        __syncthreads();
    }
    if (tid < n) partial[tid] = s[tid] - v;
}

__global__ __launch_bounds__(256) void scan_finalize(int* __restrict__ rowptr,
                                                     const int* __restrict__ partial,
                                                     const int* __restrict__ deg,
                                                     float* __restrict__ isq,
                                                     int n, int E) {
    int i = blockIdx.x * 256 + threadIdx.x;
    if (i < n) {
        rowptr[i] += partial[blockIdx.x];
        isq[i] = rsqrtf((float)deg[i] + 1.0f);
    }
    if (i == 0) rowptr[n] = E;
}

// ---------------- CSR fill: atomic-free scatter ----------------
__global__ __launch_bounds__(256) void fill_scatter(const int* __restrict__ src,
                                                    const int* __restrict__ dst,
                                                    const int* __restrict__ rank,
                                                    const int* __restrict__ rowptr,
                                                    const float* __restrict__ isq,
                                                    long long* __restrict__ edges, int E) {
    int i = blockIdx.x * 256 + threadIdx.x;
    if (i < E) {
        int d = dst[i];
        int s = src[i];
        int pos = rowptr[d] + rank[i];
        unsigned int cf = __float_as_uint(isq[s] * isq[d]);
        long long rec = (long long)(((unsigned long long)cf << 32) |
                                    (unsigned long long)(unsigned int)s);
        __builtin_nontemporal_store(rec, &edges[pos]);
    }
}

// ---------------- W pre-swizzle into B-fragment order (fp16) ----------------
// Wsw unit u = (c*8 + t)*64 + lane holds W[k=c*32+(lane>>4)*8+j][n=t*16+(lane&15)]
__global__ __launch_bounds__(256) void wswizzle(const float* __restrict__ W1,
                                                const float* __restrict__ W2,
                                                _Float16* __restrict__ W1s,
                                                _Float16* __restrict__ W2s) {
    int i = blockIdx.x * 256 + threadIdx.x;   // 0..4095
    int which = i >> 11;
    int u = i & 2047;
    int lane = u & 63, l = lane & 15, q = lane >> 4;
    int ct = u >> 6, c = ct >> 3, t = ct & 7;
    const float* Wsrc = which ? W2 : W1;
    _Float16* Dst = which ? W2s : W1s;
    half8 v;
#pragma unroll
    for (int j = 0; j < 8; j++)
        v[j] = (_Float16)Wsrc[(c * 32 + q * 8 + j) * C + t * 16 + l];
    *(half8*)(Dst + (size_t)u * 8) = v;
}

// ---------------- MFMA GEMM: out[M,128](fp16) = A[M,128] @ W ----------------
// 64 rows/block, 4 waves; wave w does rows w*16..+15 x all 128 cols via
// 8 col-tiles of mfma_f32_16x16x32_f16. A staged fp16 in LDS with granule-XOR
// swizzle; W read from pre-swizzled fragment array (L1-hot). Epilogue
// transposes C-frags through reused LDS for coalesced row stores.
template <typename T>
__global__ __launch_bounds__(256) void gemm_mfma(const T* __restrict__ A,
                                                 const _Float16* __restrict__ Wsw,
                                                 _Float16* __restrict__ out, int n) {
    __shared__ _Float16 smem[8704];   // A tile 8192 halves; epilogue 4x16x136
    int tid = threadIdx.x;
    int lane = tid & 63;
    int w = tid >> 6;
    int m0 = blockIdx.x * 64;

    // ---- stage A (64x128) to LDS fp16, granule g of row r at g^(r&15)
    if constexpr (sizeof(T) == 4) {
        const float4* A4 = (const float4*)A;
#pragma unroll
        for (int p = 0; p < 8; p++) {
            int idx = p * 256 + tid;
            int r = idx >> 5, f4 = idx & 31;
            int row = m0 + r; if (row >= n) row = n - 1;
            float4 v = A4[(size_t)row * 32 + f4];
            int kg = f4 >> 1, hi = f4 & 1;
            half4v hv = {(_Float16)v.x, (_Float16)v.y, (_Float16)v.z, (_Float16)v.w};
            *(half4v*)(smem + r * 128 + ((kg ^ (r & 15)) * 8) + hi * 4) = hv;
        }
    } else {
#pragma unroll
        for (int p = 0; p < 4; p++) {
            int idx = p * 256 + tid;
            int r = idx >> 4, kg = idx & 15;
            int row = m0 + r; if (row >= n) row = n - 1;
            half8 v = *(const half8*)(A + (size_t)row * C + kg * 8);
            *(half8*)(smem + r * 128 + ((kg ^ (r & 15)) * 8)) = v;
        }
    }
    __syncthreads();

    int l = lane & 15, q = lane >> 4;
    f32x4 acc[8] = {};

#pragma unroll
    for (int c = 0; c < 4; c++) {
        // A-frag: row = w*16 + l, k = c*32 + q*8 + j
        half8 af = *(const half8*)(smem + (w * 16 + l) * 128 + (((c * 4 + q) ^ l) * 8));
#pragma unroll
        for (int t = 0; t < 8; t++) {
            half8 bf = *(const half8*)(Wsw + (size_t)((c * 8 + t) * 64 + lane) * 8);
            acc[t] = __builtin_amdgcn_mfma_f32_16x16x32_f16(af, bf, acc[t], 0, 0, 0);
        }
    }

    __syncthreads();                       // all A reads done; reuse smem
    _Float16* cb = smem + w * 2176;        // [16][136] per wave (pad kills conflicts)
#pragma unroll
    for (int t = 0; t < 8; t++)
#pragma unroll
        for (int i = 0; i < 4; i++)        // C/D: col = t*16+l, row16 = q*4+i
            cb[(q * 4 + i) * 136 + t * 16 + l] = (_Float16)acc[t][i];
    __syncthreads();
#pragma unroll
    for (int i = 0; i < 4; i++) {
        int r16 = i * 4 + q;
        int row = m0 + w * 16 + r16;
        if (row < n)
            *(half8*)(out + (size_t)row * C + l * 8) =
                *(const half8*)(cb + r16 * 136 + l * 8);
    }
}

// ---------------- aggregation: one wave per dst node, fp16 h ----------------
// 4 quarter-waves x unroll 4 = 16 independent 256B row-gathers in flight.
template <bool RELU, typename OT>
__global__ __launch_bounds__(256) void aggregate(const _Float16* __restrict__ h,
                                                 const int* __restrict__ rowptr,
                                                 const long long* __restrict__ edges,
                                                 const float* __restrict__ isq,
                                                 const float* __restrict__ bias,
                                                 OT* __restrict__ out, int n) {
    int lane = threadIdx.x & 63;
    int wave = threadIdx.x >> 6;
    int node = blockIdx.x * 4 + wave;
    if (node >= n) return;

    int q   = lane >> 4;
    int l16 = lane & 15;
    int cb  = l16 * 8;

    int beg = rowptr[node];
    int end = rowptr[node + 1];

    float acc[8] = {};

    int j = beg + q;
    for (; j + 12 < end; j += 16) {
        unsigned long long e0 = (unsigned long long)edges[j];
        unsigned long long e1 = (unsigned long long)edges[j + 4];
        unsigned long long e2 = (unsigned long long)edges[j + 8];
        unsigned long long e3 = (unsigned long long)edges[j + 12];
        half8 h0 = *(const half8*)(h + (size_t)(unsigned int)e0 * C + cb);
        half8 h1 = *(const half8*)(h + (size_t)(unsigned int)e1 * C + cb);
        half8 h2 = *(const half8*)(h + (size_t)(unsigned int)e2 * C + cb);
        half8 h3 = *(const half8*)(h + (size_t)(unsigned int)e3 * C + cb);
        float c0 = __uint_as_float((unsigned int)(e0 >> 32));
        float c1 = __uint_as_float((unsigned int)(e1 >> 32));
        float c2 = __uint_as_float((unsigned int)(e2 >> 32));
        float c3 = __uint_as_float((unsigned int)(e3 >> 32));
#pragma unroll
        for (int k = 0; k < 8; k++) acc[k] += c0 * (float)h0[k];
#pragma unroll
        for (int k = 0; k < 8; k++) acc[k] += c1 * (float)h1[k];
#pragma unroll
        for (int k = 0; k < 8; k++) acc[k] += c2 * (float)h2[k];
#pragma unroll
        for (int k = 0; k < 8; k++) acc[k] += c3 * (float)h3[k];
    }
    for (; j < end; j += 4) {
        unsigned long long e = (unsigned long long)edges[j];
        half8 hv = *(const half8*)(h + (size_t)(unsigned int)e * C + cb);
        float cf = __uint_as_float((unsigned int)(e >> 32));
#pragma unroll
        for (int k = 0; k < 8; k++) acc[k] += cf * (float)hv[k];
    }

#pragma unroll
    for (int k = 0; k < 8; k++) {
        acc[k] += __shfl_xor(acc[k], 16, 64);
        acc[k] += __shfl_xor(acc[k], 32, 64);
    }

    if (q == 0) {
        float invd = isq[node];
        float sc = invd * invd;                     // self-loop coef = 1/deg
        half8 hd = *(const half8*)(h + (size_t)node * C + cb);
        float4 bv0 = *(const float4*)(bias + cb);
        float4 bv1 = *(const float4*)(bias + cb + 4);
        float bb[8] = {bv0.x, bv0.y, bv0.z, bv0.w, bv1.x, bv1.y, bv1.z, bv1.w};
#pragma unroll
        for (int k = 0; k < 8; k++) {
            acc[k] += sc * (float)hd[k] + bb[k];
            if (RELU) acc[k] = fmaxf(acc[k], 0.f);
        }
        if constexpr (sizeof(OT) == 2) {
            half8 o;
#pragma unroll
            for (int k = 0; k < 8; k++) o[k] = (_Float16)acc[k];
            *(half8*)((_Float16*)out + (size_t)node * C + cb) = o;
        } else {
            float4 o0 = {acc[0], acc[1], acc[2], acc[3]};
            float4 o1 = {acc[4], acc[5], acc[6], acc[7]};
            *(float4*)((float*)out + (size_t)node * C + cb) = o0;
            *(float4*)((float*)out + (size_t)node * C + cb + 4) = o1;
        }
    }
}

extern "C" void kernel_launch(void* const* d_in, const int* in_sizes, int n_in,
                              void* d_out, int out_size, void* d_ws, size_t ws_size,
                              hipStream_t stream) {
    const float* x  = (const float*)d_in[0];
    const int* ei   = (const int*)d_in[1];   // [2, E] int
    const float* W1 = (const float*)d_in[2];
    const float* b1 = (const float*)d_in[3];
    const float* W2 = (const float*)d_in[4];
    const float* b2 = (const float*)d_in[5];
    float* out = (float*)d_out;

    const int N = N_NODES, E = N_EDGES;
    const int* src = ei;
    const int* dst = ei + E;

    char* ws = (char*)d_ws;
    size_t off = 0;
    auto alloc = [&](size_t bytes) {
        size_t o = off;
        off = (off + bytes + 255) & ~(size_t)255;
        return o;
    };
    _Float16* h16   = (_Float16*)(ws + alloc((size_t)N * C * 2));  // gemm out / agg in
    _Float16* hB16  = (_Float16*)(ws + alloc((size_t)N * C * 2));  // agg1 out / gemm2 in
    _Float16* W1s   = (_Float16*)(ws + alloc((size_t)C * C * 2));
    _Float16* W2s   = (_Float16*)(ws + alloc((size_t)C * C * 2));
    int*      deg   = (int*)     (ws + alloc((size_t)N * 4));
    float*    isq   = (float*)   (ws + alloc((size_t)N * 4));
    int*    rowptr  = (int*)     (ws + alloc((size_t)(N + 1) * 4));
    int*    rank    = (int*)     (ws + alloc((size_t)E * 4));
    int*    part    = (int*)     (ws + alloc((size_t)512 * 4));
    long long* edges = (long long*)(ws + alloc((size_t)E * 8));
    (void)ws_size; (void)n_in; (void)in_sizes; (void)out_size;

    const int nbN = (N + 255) / 256;   // 391
    const int nbE = (E + 255) / 256;   // 6250
    const int nbG = (N + 63) / 64;     // 1563

    (void)hipMemsetAsync(deg, 0, (size_t)N * 4, stream);
    deg_rank<<<nbE, 256, 0, stream>>>(dst, deg, rank, E);

    wswizzle<<<16, 256, 0, stream>>>(W1, W2, W1s, W2s);

    scan_block<<<nbN, 256, 0, stream>>>(deg, rowptr, part, N);
    scan_partial<<<1, 512, 0, stream>>>(part, nbN);
    scan_finalize<<<nbN, 256, 0, stream>>>(rowptr, part, deg, isq, N, E);
    fill_scatter<<<nbE, 256, 0, stream>>>(src, dst, rank, rowptr, isq, edges, E);

    // layer 1
    gemm_mfma<float><<<nbG, 256, 0, stream>>>(x, W1s, h16, N);
    aggregate<true, _Float16><<<(N + 3) / 4, 256, 0, stream>>>(h16, rowptr, edges, isq, b1, hB16, N);

    // layer 2
    gemm_mfma<_Float16><<<nbG, 256, 0, stream>>>(hB16, W2s, h16, N);
    aggregate<false, float><<<(N + 3) / 4, 256, 0, stream>>>(h16, rowptr, edges, isq, b2, out, N);
}

// Round 7
// 384.310 us; speedup vs baseline: 1.9645x; 1.0304x over previous
//
#include <hip/hip_runtime.h>
#include <hip/hip_bf16.h>
#include <hip/hip_fp16.h>

#define N_NODES 100000
#define N_EDGES 1600000
#define C 128

typedef _Float16 half8 __attribute__((ext_vector_type(8)));
typedef _Float16 half4v __attribute__((ext_vector_type(4)));
typedef float f32x4 __attribute__((ext_vector_type(4)));

// ---------------- exclusive scan (3-kernel) ----------------
__global__ __launch_bounds__(256) void scan_block(const int* __restrict__ deg,
                                                  int* __restrict__ rowptr,
                                                  int* __restrict__ partial, int n) {
    __shared__ int s[256];
    int tid = threadIdx.x;
    int i = blockIdx.x * 256 + tid;
    int v = (i < n) ? deg[i] : 0;
    s[tid] = v;
    __syncthreads();
    for (int off = 1; off < 256; off <<= 1) {
        int t = (tid >= off) ? s[tid - off] : 0;
        __syncthreads();
        s[tid] += t;
        __syncthreads();
    }
    if (i < n) rowptr[i] = s[tid] - v;
    if (tid == 255) partial[blockIdx.x] = s[255];
}

__global__ __launch_bounds__(512) void scan_partial(int* __restrict__ partial, int n) {
    __shared__ int s[512];
    int tid = threadIdx.x;
    int v = (tid < n) ? partial[tid] : 0;
    s[tid] = v;
    __syncthreads();
    for (int off = 1; off < 512; off <<= 1) {
        int t = (tid >= off) ? s[tid - off] : 0;
        __syncthreads();
        s[tid] += t;
        __syncthreads();
    }
    if (tid < n) partial[tid] = s[tid] - v;
}

__global__ __launch_bounds__(256) void scan_finalize(int* __restrict__ rowptr,
                                                     const int* __restrict__ partial,
                                                     const int* __restrict__ deg,
                                                     float* __restrict__ isq,
                                                     int n, int E) {
    int i = blockIdx.x * 256 + threadIdx.x;
    if (i < n) {
        rowptr[i] += partial[blockIdx.x];
        isq[i] = rsqrtf((float)deg[i] + 1.0f);
    }
    if (i == 0) rowptr[n] = E;
}

// ---------------- CSR fill: atomic-free scatter ----------------
__global__ __launch_bounds__(256) void fill_scatter(const int* __restrict__ src,
                                                    const int* __restrict__ dst,
                                                    const int* __restrict__ rank,
                                                    const int* __restrict__ rowptr,
                                                    const float* __restrict__ isq,
                                                    long long* __restrict__ edges, int E) {
    int i = blockIdx.x * 256 + threadIdx.x;
    if (i < E) {
        int d = dst[i];
        int s = src[i];
        int pos = rowptr[d] + rank[i];
        unsigned int cf = __float_as_uint(isq[s] * isq[d]);
        long long rec = (long long)(((unsigned long long)cf << 32) |
                                    (unsigned long long)(unsigned int)s);
        __builtin_nontemporal_store(rec, &edges[pos]);
    }
}

// ---------------- init: W pre-swizzle (blocks 0..15) + deg zero (rest) ------
// Wsw unit u = (c*8 + t)*64 + lane holds W[k=c*32+(lane>>4)*8+j][n=t*16+(lane&15)]
__global__ __launch_bounds__(256) void init_kernel(const float* __restrict__ W1,
                                                   const float* __restrict__ W2,
                                                   _Float16* __restrict__ W1s,
                                                   _Float16* __restrict__ W2s,
                                                   int* __restrict__ deg, int n) {
    if (blockIdx.x < 16) {
        int i = blockIdx.x * 256 + threadIdx.x;   // 0..4095
        int which = i >> 11;
        int u = i & 2047;
        int lane = u & 63, l = lane & 15, q = lane >> 4;
        int ct = u >> 6, c = ct >> 3, t = ct & 7;
        const float* Wsrc = which ? W2 : W1;
        _Float16* Dst = which ? W2s : W1s;
        half8 v;
#pragma unroll
        for (int j = 0; j < 8; j++)
            v[j] = (_Float16)Wsrc[(c * 32 + q * 8 + j) * C + t * 16 + l];
        *(half8*)(Dst + (size_t)u * 8) = v;
    } else {
        int i = (blockIdx.x - 16) * 256 + threadIdx.x;
        if (i < n) deg[i] = 0;
    }
}

// ---------------- MFMA GEMM body (device fn, shared by 2 kernels) ----------
template <typename T>
__device__ __forceinline__ void gemm_body(const T* __restrict__ A,
                                          const _Float16* __restrict__ Wsw,
                                          _Float16* __restrict__ out, int n,
                                          int bid, int tid, _Float16* smem) {
    int lane = tid & 63;
    int w = tid >> 6;
    int m0 = bid * 64;

    // ---- stage A (64x128) to LDS fp16, granule g of row r at g^(r&15)
    if constexpr (sizeof(T) == 4) {
        const float4* A4 = (const float4*)A;
#pragma unroll
        for (int p = 0; p < 8; p++) {
            int idx = p * 256 + tid;
            int r = idx >> 5, f4 = idx & 31;
            int row = m0 + r; if (row >= n) row = n - 1;
            float4 v = A4[(size_t)row * 32 + f4];
            int kg = f4 >> 1, hi = f4 & 1;
            half4v hv = {(_Float16)v.x, (_Float16)v.y, (_Float16)v.z, (_Float16)v.w};
            *(half4v*)(smem + r * 128 + ((kg ^ (r & 15)) * 8) + hi * 4) = hv;
        }
    } else {
#pragma unroll
        for (int p = 0; p < 4; p++) {
            int idx = p * 256 + tid;
            int r = idx >> 4, kg = idx & 15;
            int row = m0 + r; if (row >= n) row = n - 1;
            half8 v = *(const half8*)(A + (size_t)row * C + kg * 8);
            *(half8*)(smem + r * 128 + ((kg ^ (r & 15)) * 8)) = v;
        }
    }
    __syncthreads();

    int l = lane & 15, q = lane >> 4;
    f32x4 acc[8] = {};

#pragma unroll
    for (int c = 0; c < 4; c++) {
        half8 af = *(const half8*)(smem + (w * 16 + l) * 128 + (((c * 4 + q) ^ l) * 8));
#pragma unroll
        for (int t = 0; t < 8; t++) {
            half8 bf = *(const half8*)(Wsw + (size_t)((c * 8 + t) * 64 + lane) * 8);
            acc[t] = __builtin_amdgcn_mfma_f32_16x16x32_f16(af, bf, acc[t], 0, 0, 0);
        }
    }

    __syncthreads();                       // all A reads done; reuse smem
    _Float16* cb = smem + w * 2176;        // [16][136] per wave
#pragma unroll
    for (int t = 0; t < 8; t++)
#pragma unroll
        for (int i = 0; i < 4; i++)        // C/D: col = t*16+l, row16 = q*4+i
            cb[(q * 4 + i) * 136 + t * 16 + l] = (_Float16)acc[t][i];
    __syncthreads();
#pragma unroll
    for (int i = 0; i < 4; i++) {
        int r16 = i * 4 + q;
        int row = m0 + w * 16 + r16;
        if (row < n)
            *(half8*)(out + (size_t)row * C + l * 8) =
                *(const half8*)(cb + r16 * 136 + l * 8);
    }
}

template <typename T>
__global__ __launch_bounds__(256) void gemm_mfma(const T* __restrict__ A,
                                                 const _Float16* __restrict__ Wsw,
                                                 _Float16* __restrict__ out, int n) {
    __shared__ _Float16 smem[8704];
    gemm_body<T>(A, Wsw, out, n, blockIdx.x, threadIdx.x, smem);
}

// ---------------- fused: gemm layer-1 (blocks < nbG) + deg_rank (rest) ------
// gemm1 has no dependency on the CSR build; co-scheduling hides the
// atomic-latency-bound deg_rank behind MFMA work (pipes overlap, m114).
__global__ __launch_bounds__(256) void fused_deg_gemm(const float* __restrict__ x,
                                                      const _Float16* __restrict__ W1s,
                                                      _Float16* __restrict__ h16, int n,
                                                      const int* __restrict__ dst,
                                                      int* __restrict__ deg,
                                                      int* __restrict__ rank, int E,
                                                      int nbG) {
    __shared__ _Float16 smem[8704];
    if ((int)blockIdx.x < nbG) {
        gemm_body<float>(x, W1s, h16, n, blockIdx.x, threadIdx.x, smem);
    } else {
        int i = (blockIdx.x - nbG) * 256 + threadIdx.x;
        if (i < E) rank[i] = atomicAdd(&deg[dst[i]], 1);
    }
}

// ---------------- aggregation: one wave per dst node, fp16 h ----------------
template <bool RELU, typename OT>
__global__ __launch_bounds__(256) void aggregate(const _Float16* __restrict__ h,
                                                 const int* __restrict__ rowptr,
                                                 const long long* __restrict__ edges,
                                                 const float* __restrict__ isq,
                                                 const float* __restrict__ bias,
                                                 OT* __restrict__ out, int n) {
    int lane = threadIdx.x & 63;
    int wave = threadIdx.x >> 6;
    int node = blockIdx.x * 4 + wave;
    if (node >= n) return;

    int q   = lane >> 4;
    int l16 = lane & 15;
    int cb  = l16 * 8;

    int beg = rowptr[node];
    int end = rowptr[node + 1];

    float acc[8] = {};

    int j = beg + q;
    for (; j + 12 < end; j += 16) {
        unsigned long long e0 = (unsigned long long)edges[j];
        unsigned long long e1 = (unsigned long long)edges[j + 4];
        unsigned long long e2 = (unsigned long long)edges[j + 8];
        unsigned long long e3 = (unsigned long long)edges[j + 12];
        half8 h0 = *(const half8*)(h + (size_t)(unsigned int)e0 * C + cb);
        half8 h1 = *(const half8*)(h + (size_t)(unsigned int)e1 * C + cb);
        half8 h2 = *(const half8*)(h + (size_t)(unsigned int)e2 * C + cb);
        half8 h3 = *(const half8*)(h + (size_t)(unsigned int)e3 * C + cb);
        float c0 = __uint_as_float((unsigned int)(e0 >> 32));
        float c1 = __uint_as_float((unsigned int)(e1 >> 32));
        float c2 = __uint_as_float((unsigned int)(e2 >> 32));
        float c3 = __uint_as_float((unsigned int)(e3 >> 32));
#pragma unroll
        for (int k = 0; k < 8; k++) acc[k] += c0 * (float)h0[k];
#pragma unroll
        for (int k = 0; k < 8; k++) acc[k] += c1 * (float)h1[k];
#pragma unroll
        for (int k = 0; k < 8; k++) acc[k] += c2 * (float)h2[k];
#pragma unroll
        for (int k = 0; k < 8; k++) acc[k] += c3 * (float)h3[k];
    }
    for (; j < end; j += 4) {
        unsigned long long e = (unsigned long long)edges[j];
        half8 hv = *(const half8*)(h + (size_t)(unsigned int)e * C + cb);
        float cf = __uint_as_float((unsigned int)(e >> 32));
#pragma unroll
        for (int k = 0; k < 8; k++) acc[k] += cf * (float)hv[k];
    }

#pragma unroll
    for (int k = 0; k < 8; k++) {
        acc[k] += __shfl_xor(acc[k], 16, 64);
        acc[k] += __shfl_xor(acc[k], 32, 64);
    }

    if (q == 0) {
        float invd = isq[node];
        float sc = invd * invd;                     // self-loop coef = 1/deg
        half8 hd = *(const half8*)(h + (size_t)node * C + cb);
        float4 bv0 = *(const float4*)(bias + cb);
        float4 bv1 = *(const float4*)(bias + cb + 4);
        float bb[8] = {bv0.x, bv0.y, bv0.z, bv0.w, bv1.x, bv1.y, bv1.z, bv1.w};
#pragma unroll
        for (int k = 0; k < 8; k++) {
            acc[k] += sc * (float)hd[k] + bb[k];
            if (RELU) acc[k] = fmaxf(acc[k], 0.f);
        }
        if constexpr (sizeof(OT) == 2) {
            half8 o;
#pragma unroll
            for (int k = 0; k < 8; k++) o[k] = (_Float16)acc[k];
            *(half8*)((_Float16*)out + (size_t)node * C + cb) = o;
        } else {
            float4 o0 = {acc[0], acc[1], acc[2], acc[3]};
            float4 o1 = {acc[4], acc[5], acc[6], acc[7]};
            *(float4*)((float*)out + (size_t)node * C + cb) = o0;
            *(float4*)((float*)out + (size_t)node * C + cb + 4) = o1;
        }
    }
}

extern "C" void kernel_launch(void* const* d_in, const int* in_sizes, int n_in,
                              void* d_out, int out_size, void* d_ws, size_t ws_size,
                              hipStream_t stream) {
    const float* x  = (const float*)d_in[0];
    const int* ei   = (const int*)d_in[1];   // [2, E] int
    const float* W1 = (const float*)d_in[2];
    const float* b1 = (const float*)d_in[3];
    const float* W2 = (const float*)d_in[4];
    const float* b2 = (const float*)d_in[5];
    float* out = (float*)d_out;

    const int N = N_NODES, E = N_EDGES;
    const int* src = ei;
    const int* dst = ei + E;

    char* ws = (char*)d_ws;
    size_t off = 0;
    auto alloc = [&](size_t bytes) {
        size_t o = off;
        off = (off + bytes + 255) & ~(size_t)255;
        return o;
    };
    _Float16* h16   = (_Float16*)(ws + alloc((size_t)N * C * 2));  // gemm out / agg in
    _Float16* hB16  = (_Float16*)(ws + alloc((size_t)N * C * 2));  // agg1 out / gemm2 in
    _Float16* W1s   = (_Float16*)(ws + alloc((size_t)C * C * 2));
    _Float16* W2s   = (_Float16*)(ws + alloc((size_t)C * C * 2));
    int*      deg   = (int*)     (ws + alloc((size_t)N * 4));
    float*    isq   = (float*)   (ws + alloc((size_t)N * 4));
    int*    rowptr  = (int*)     (ws + alloc((size_t)(N + 1) * 4));
    int*    rank    = (int*)     (ws + alloc((size_t)E * 4));
    int*    part    = (int*)     (ws + alloc((size_t)512 * 4));
    long long* edges = (long long*)(ws + alloc((size_t)E * 8));
    (void)ws_size; (void)n_in; (void)in_sizes; (void)out_size;

    const int nbN = (N + 255) / 256;   // 391
    const int nbE = (E + 255) / 256;   // 6250
    const int nbG = (N + 63) / 64;     // 1563

    // 1: W swizzle + deg zeroing (one launch, independent halves)
    init_kernel<<<16 + nbN, 256, 0, stream>>>(W1, W2, W1s, W2s, deg, N);

    // 2: gemm layer-1 co-scheduled with deg_rank (independent work)
    fused_deg_gemm<<<nbG + nbE, 256, 0, stream>>>(x, W1s, h16, N, dst, deg, rank, E, nbG);

    // 3-5: CSR scan
    scan_block<<<nbN, 256, 0, stream>>>(deg, rowptr, part, N);
    scan_partial<<<1, 512, 0, stream>>>(part, nbN);
    scan_finalize<<<nbN, 256, 0, stream>>>(rowptr, part, deg, isq, N, E);

    // 6: atomic-free CSR fill (pos = rowptr[dst] + rank)
    fill_scatter<<<nbE, 256, 0, stream>>>(src, dst, rank, rowptr, isq, edges, E);

    // 7: layer-1 aggregation (fp16 out)
    aggregate<true, _Float16><<<(N + 3) / 4, 256, 0, stream>>>(h16, rowptr, edges, isq, b1, hB16, N);

    // 8: layer-2 GEMM
    gemm_mfma<_Float16><<<nbG, 256, 0, stream>>>(hB16, W2s, h16, N);

    // 9: layer-2 aggregation (fp32 out)
    aggregate<false, float><<<(N + 3) / 4, 256, 0, stream>>>(h16, rowptr, edges, isq, b2, out, N);
}